// Round 1
// baseline (584.426 us; speedup 1.0000x reference)
//
#include <hip/hip_runtime.h>

// MoE switch layer: B=8, N=2048, D=1024, E=8, DFF=4096, CAP=320
#define Bq 8
#define Nq 2048
#define Dq 1024
#define Eq 8
#define DFFq 4096
#define CAPq 320
#define Mq (Bq * CAPq)   // 2560 rows per expert
#define Tq (Bq * Nq)     // 16384 tokens

typedef __attribute__((ext_vector_type(8))) short bf16x8;
typedef __attribute__((ext_vector_type(4))) float f32x4;

static __device__ __forceinline__ unsigned short f2bf(float f) {
    union { float f; unsigned u; } v;
    v.f = f;
    unsigned r = v.u + 0x7fffu + ((v.u >> 16) & 1u);   // RNE
    return (unsigned short)(r >> 16);
}

static __device__ __forceinline__ void gload_lds16(const void* g, void* l) {
    __builtin_amdgcn_global_load_lds(
        (const __attribute__((address_space(1))) unsigned int*)g,
        (__attribute__((address_space(3))) unsigned int*)l, 16, 0, 0);
}

// ---------------- routing: logits -> softmax -> argmax/gate ----------------
__global__ __launch_bounds__(256) void route_kernel(
    const float* __restrict__ tok, const float* __restrict__ Wg,
    int* __restrict__ eidx, float* __restrict__ gate)
{
    int wv = threadIdx.x >> 6, lane = threadIdx.x & 63;
    int t = blockIdx.x * 4 + wv;
    const float* tp = tok + (size_t)t * Dq;
    float acc[8] = {0.f,0.f,0.f,0.f,0.f,0.f,0.f,0.f};
    for (int it = 0; it < Dq / 64; ++it) {
        int d = it * 64 + lane;
        float x = tp[d];
        const float4* w = (const float4*)(Wg + (size_t)d * 8);
        float4 w0 = w[0], w1 = w[1];
        acc[0] += x * w0.x; acc[1] += x * w0.y; acc[2] += x * w0.z; acc[3] += x * w0.w;
        acc[4] += x * w1.x; acc[5] += x * w1.y; acc[6] += x * w1.z; acc[7] += x * w1.w;
    }
#pragma unroll
    for (int e = 0; e < 8; ++e)
#pragma unroll
        for (int off = 32; off; off >>= 1)
            acc[e] += __shfl_xor(acc[e], off, 64);
    if (lane == 0) {
        float m = acc[0]; int bi = 0;
#pragma unroll
        for (int e = 1; e < 8; ++e) if (acc[e] > m) { m = acc[e]; bi = e; }
        float s = 0.f;
#pragma unroll
        for (int e = 0; e < 8; ++e) s += expf(acc[e] - m);
        eidx[t] = bi;
        gate[t] = 1.0f / s;   // max prob
    }
}

// ------------- slot assignment: cumsum-order scan per (b,e) ----------------
__global__ __launch_bounds__(64) void slot_kernel(
    const int* __restrict__ eidx, int* __restrict__ tfs)
{
    int b = blockIdx.x >> 3, e = blockIdx.x & 7;
    int lane = threadIdx.x;
    const int* ip = eidx + (size_t)b * Nq;
    int base = (e * Bq + b) * CAPq;
    int cnt = 0;
    for (int it = 0; it < Nq / 64; ++it) {
        int n = it * 64 + lane;
        bool my = (ip[n] == e);
        unsigned long long mask = __ballot(my);
        if (my) {
            int pos = cnt + __popcll(mask & ((1ull << lane) - 1ull));
            if (pos < CAPq) tfs[base + pos] = b * Nq + n;
        }
        cnt += __popcll(mask);
    }
}

// ------------- dispatch: gather token rows -> bf16 expert buffers ----------
__global__ __launch_bounds__(128) void dispatch_kernel(
    const float* __restrict__ tok, const int* __restrict__ tfs,
    unsigned short* __restrict__ X)
{
    int r = blockIdx.x;          // 0 .. E*B*CAP-1
    int t = tfs[r];
    int d0 = threadIdx.x * 8;
    unsigned short o[8];
    if (t < 0) {
#pragma unroll
        for (int k = 0; k < 8; ++k) o[k] = 0;
    } else {
        const float4* p = (const float4*)(tok + (size_t)t * Dq + d0);
        float4 a = p[0], b = p[1];
        o[0]=f2bf(a.x); o[1]=f2bf(a.y); o[2]=f2bf(a.z); o[3]=f2bf(a.w);
        o[4]=f2bf(b.x); o[5]=f2bf(b.y); o[6]=f2bf(b.z); o[7]=f2bf(b.w);
    }
    *(uint4*)(X + (size_t)r * Dq + d0) = *(const uint4*)o;
}

// ------- weight transpose+convert: in [E][R][C] f32 -> out [E][C][R] bf16 --
__global__ __launch_bounds__(256) void transpose_cvt(
    const float* __restrict__ in, unsigned short* __restrict__ out,
    int R, int C)
{
    __shared__ float tile[32][33];
    int e = blockIdx.z;
    int c0 = blockIdx.x * 32, r0 = blockIdx.y * 32;
    int tx = threadIdx.x & 31, ty = threadIdx.x >> 5;
    const float* ip = in + (size_t)e * R * C;
#pragma unroll
    for (int rr = 0; rr < 4; ++rr)
        tile[ty + rr * 8][tx] = ip[(size_t)(r0 + ty + rr * 8) * C + c0 + tx];
    __syncthreads();
    unsigned short* op = out + (size_t)e * R * C;
#pragma unroll
    for (int rr = 0; rr < 4; ++rr)
        op[(size_t)(c0 + ty + rr * 8) * R + r0 + tx] = f2bf(tile[tx][ty + rr * 8]);
}

// ---------------- NT GEMM: C[M][N] = A[M][K] * Bt[N][K]^T -------------------
// MODE 0: H = relu(C) as bf16.  MODE 1: scatter rows to Out with gate.
template <int MODE>
__global__ __launch_bounds__(256) void gemm_nt(
    const unsigned short* __restrict__ A,   // [E][M][K] bf16
    const unsigned short* __restrict__ Bt,  // [E][N][K] bf16
    unsigned short* __restrict__ Hout,      // [E][M][N] bf16  (MODE 0)
    float* __restrict__ Out,                // [T][D] f32      (MODE 1)
    const int* __restrict__ tfs,            // [E][M]
    const float* __restrict__ gate,         // [T]
    int M, int N, int K)
{
    __shared__ __align__(16) unsigned short As[128 * 64];
    __shared__ __align__(16) unsigned short Bs[128 * 64];
    __shared__ int   t_lds[128];
    __shared__ float g_lds[128];

    const int tid = threadIdx.x;
    const int e  = blockIdx.z;
    const int n0 = blockIdx.x * 128;
    const int m0 = blockIdx.y * 128;
    const unsigned short* Ae = A  + (size_t)e * M * K + (size_t)m0 * K;
    const unsigned short* Be = Bt + (size_t)e * N * K + (size_t)n0 * K;

    if (MODE == 1 && tid < 128) {
        int t = tfs[e * M + m0 + tid];
        t_lds[tid] = t;
        g_lds[tid] = (t >= 0) ? gate[t] : 0.f;
    }

    const int lane = tid & 63;
    const int wv = tid >> 6;
    const int wr = wv >> 1, wc = wv & 1;
    const int lrow = lane & 15;
    const int lk = lane >> 4;
    const int swz = (lrow & 7) << 4;

    // staging decode (constant per thread): LDS off = inst*4096 + tid*16
    const int srow = tid >> 3;                                     // row within 32-row chunk
    const int skb  = ((tid & 7) << 4) ^ (((tid >> 3) & 7) << 4);   // pre-swizzled src byte
    const int ldst = (tid >> 6) << 10;                             // wave-uniform dest

    f32x4 acc[4][4] = {};

    for (int kt = 0; kt < K; kt += 64) {
        __syncthreads();
        const char* ga = (const char*)Ae + ((size_t)srow * K + kt) * 2 + skb;
        const char* gb = (const char*)Be + ((size_t)srow * K + kt) * 2 + skb;
#pragma unroll
        for (int inst = 0; inst < 4; ++inst) {
            gload_lds16(ga + (size_t)(inst * 32) * K * 2, (char*)As + inst * 4096 + ldst);
            gload_lds16(gb + (size_t)(inst * 32) * K * 2, (char*)Bs + inst * 4096 + ldst);
        }
        __syncthreads();
#pragma unroll
        for (int kk = 0; kk < 2; ++kk) {
            bf16x8 af[4], bfr[4];
#pragma unroll
            for (int i = 0; i < 4; ++i) {
                int row = wr * 64 + i * 16 + lrow;
                int addr = row * 128 + ((kk * 64 + lk * 16) ^ swz);
                af[i] = *(const bf16x8*)((const char*)As + addr);
            }
#pragma unroll
            for (int j = 0; j < 4; ++j) {
                int row = wc * 64 + j * 16 + lrow;
                int addr = row * 128 + ((kk * 64 + lk * 16) ^ swz);
                bfr[j] = *(const bf16x8*)((const char*)Bs + addr);
            }
#pragma unroll
            for (int i = 0; i < 4; ++i)
#pragma unroll
                for (int j = 0; j < 4; ++j)
                    acc[i][j] = __builtin_amdgcn_mfma_f32_16x16x32_bf16(
                        af[i], bfr[j], acc[i][j], 0, 0, 0);
        }
    }

    if (MODE == 0) {
        unsigned short* Hp = Hout + (size_t)e * M * N;
#pragma unroll
        for (int i = 0; i < 4; ++i) {
            int row = m0 + wr * 64 + i * 16 + lk * 4;
#pragma unroll
            for (int j = 0; j < 4; ++j) {
                int col = n0 + wc * 64 + j * 16 + lrow;
#pragma unroll
                for (int r = 0; r < 4; ++r)
                    Hp[(size_t)(row + r) * N + col] = f2bf(fmaxf(acc[i][j][r], 0.f));
            }
        }
    } else {
#pragma unroll
        for (int i = 0; i < 4; ++i) {
            int rowl = wr * 64 + i * 16 + lk * 4;
#pragma unroll
            for (int r = 0; r < 4; ++r) {
                int t = t_lds[rowl + r];
                if (t < 0) continue;
                float g = g_lds[rowl + r];
#pragma unroll
                for (int j = 0; j < 4; ++j) {
                    int col = n0 + wc * 64 + j * 16 + lrow;
                    Out[(size_t)t * Dq + col] = g * acc[i][j][r];
                }
            }
        }
    }
}

// ---------------------------------------------------------------------------
extern "C" void kernel_launch(void* const* d_in, const int* in_sizes, int n_in,
                              void* d_out, int out_size, void* d_ws, size_t ws_size,
                              hipStream_t stream)
{
    const float* tok = (const float*)d_in[0];
    const float* Wg  = (const float*)d_in[1];
    const float* W1  = (const float*)d_in[2];
    const float* W2  = (const float*)d_in[3];
    float* out = (float*)d_out;
    char* ws = (char*)d_ws;

    // workspace layout (bytes)
    unsigned short* W1T = (unsigned short*)(ws);                    // [E][DFF][D] bf16  67108864
    unsigned short* W2T = (unsigned short*)(ws + 67108864);         // [E][D][DFF] bf16  67108864
    unsigned short* X   = (unsigned short*)(ws + 134217728);        // [E][M][D]  bf16   41943040
    unsigned short* H   = (unsigned short*)(ws + 176160768);        // [E][M][DFF] bf16 167772160
    int*   tfs  = (int*)(ws + 343932928);                           // [E][M]            81920
    int*   eidx = (int*)(ws + 344014848);                           // [T]               65536
    float* gate = (float*)(ws + 344080384);                         // [T]               65536

    hipMemsetAsync(d_out, 0, (size_t)out_size * 4, stream);
    hipMemsetAsync(tfs, 0xFF, Eq * Mq * 4, stream);

    route_kernel<<<Tq / 4, 256, 0, stream>>>(tok, Wg, eidx, gate);
    slot_kernel<<<Bq * Eq, 64, 0, stream>>>(eidx, tfs);
    dispatch_kernel<<<Eq * Mq, 128, 0, stream>>>(tok, tfs, X);
    transpose_cvt<<<dim3(DFFq / 32, Dq / 32, Eq), 256, 0, stream>>>(W1, W1T, Dq, DFFq);
    transpose_cvt<<<dim3(Dq / 32, DFFq / 32, Eq), 256, 0, stream>>>(W2, W2T, DFFq, Dq);

    gemm_nt<0><<<dim3(DFFq / 128, Mq / 128, Eq), 256, 0, stream>>>(
        X, W1T, H, nullptr, nullptr, nullptr, Mq, DFFq, Dq);
    gemm_nt<1><<<dim3(Dq / 128, Mq / 128, Eq), 256, 0, stream>>>(
        H, W2T, nullptr, out, tfs, gate, Mq, Dq, DFFq);
}